// Round 1
// baseline (108.265 us; speedup 1.0000x reference)
//
#include <hip/hip_runtime.h>
#include <hip/hip_bf16.h>

// Modulated conv2d (StyleGAN2) on MI355X.
// Rewrite: out[b,o] = rsig[b,o] * conv(s[b,:]*x[b,:], W*SCALE)   (shared weights!)
//          rsig[b,o] = 1/sqrt(sum_i s[b,i]^2 * wsq[o,i] + 1e-8)
// Conv as implicit GEMM: D[o][p] = sum_k Wb[o][k] * Xcl[p][k],
//   k = tap*512 + ci,  Xcl = channels-last halo-padded input (zero halo ->
//   every tap is a pure pointer offset, no boundary masking).

typedef __attribute__((ext_vector_type(4))) float f32x4;
typedef __attribute__((ext_vector_type(8))) short bf16x8;

#define NB    16
#define CIN   512
#define COUT  512
#define KTOT  4608          // CIN * 9
#define NPIX  (NB * 32 * 32) // 16384

__device__ __forceinline__ void gload_lds16(const void* g, void* l) {
  __builtin_amdgcn_global_load_lds(
      (__attribute__((address_space(1))) void*)(g),
      (__attribute__((address_space(3))) void*)(l), 16, 0, 0);
}

// ---------------- kernel 1: pack weights (bf16, [o][tap*512+ci]) + wsq ----------------
__global__ __launch_bounds__(256) void pack_w_kernel(
    const float* __restrict__ w, __hip_bfloat16* __restrict__ wB,
    float* __restrict__ wsq) {
  const int idx = blockIdx.x * 256 + threadIdx.x;   // = o*512 + ci
  const int o = idx >> 9, ci = idx & 511;
  const float* wp = w + (size_t)idx * 9;
  const float WSCALE = 0.014731391274719739f;       // 1/sqrt(512*9)
  float sum = 0.f;
#pragma unroll
  for (int t = 0; t < 9; ++t) {
    float v = wp[t] * WSCALE;
    sum += v * v;
    wB[(size_t)o * KTOT + t * 512 + ci] = __float2bfloat16(v);
  }
  wsq[idx] = sum;
}

// ---------------- kernel 2: rsig[b][o], one wave per (b,o) ----------------
__global__ __launch_bounds__(256) void calc_rsig_kernel(
    const float* __restrict__ s, const float* __restrict__ wsq,
    float* __restrict__ rsig) {
  const int wid = blockIdx.x * 4 + (threadIdx.x >> 6); // b*512 + o
  const int lane = threadIdx.x & 63;
  const int b = wid >> 9, o = wid & 511;
  const float* sp = s + b * 512;
  const float* wp = wsq + o * 512;
  float sum = 0.f;
#pragma unroll
  for (int i = 0; i < 8; ++i) {
    float sv = sp[lane + i * 64];
    sum += sv * sv * wp[lane + i * 64];
  }
#pragma unroll
  for (int off = 32; off > 0; off >>= 1) sum += __shfl_down(sum, off, 64);
  if (lane == 0) rsig[wid] = 1.0f / sqrtf(sum + 1e-8f);
}

// ---------------- kernel 3: modulate + NCHW->padded channels-last bf16 ----------------
// xpad[b][y+1][x+1][ci] = bf16(s[b,ci] * x[b,ci,y,x]); halo stays 0 (memset).
__global__ __launch_bounds__(256) void modulate_kernel(
    const float* __restrict__ x, const float* __restrict__ s,
    __hip_bfloat16* __restrict__ xpad) {
  const int by = blockIdx.x;            // b*32 + y
  const int b = by >> 5, y = by & 31;
  __shared__ __attribute__((aligned(16))) __hip_bfloat16 tile[32][72];
  const int tid = threadIdx.x;
  const int xc = tid & 31;
  const int cr0 = tid >> 5;             // 0..7
  const float* xrow = x + ((size_t)b * 512 * 32 + y) * 32; // + ci*1024 + xc
  const float* sb = s + b * 512;
  __hip_bfloat16* orow = xpad + (size_t)((b * 34 + y + 1) * 34) * 512;

  for (int ci0 = 0; ci0 < 512; ci0 += 64) {
#pragma unroll
    for (int r = 0; r < 8; ++r) {
      const int cir = r * 8 + cr0;
      const int ci = ci0 + cir;
      float v = xrow[(size_t)ci * 1024 + xc] * sb[ci];
      tile[xc][cir] = __float2bfloat16(v);
    }
    __syncthreads();
    const int xcw = tid >> 3, vec = tid & 7;
    bf16x8 v = *(const bf16x8*)&tile[xcw][vec * 8];
    *(bf16x8*)(orow + (size_t)(xcw + 1) * 512 + ci0 + vec * 8) = v;
    __syncthreads();
  }
}

// ---------------- kernel 4: implicit-GEMM conv ----------------
// Tile: 128 cout x 128 pixels, BK=64. 4 waves (2x2), each 64x64 via 4x4
// mfma_f32_16x16x32_bf16. global_load_lds w=16 staging, linear LDS dest +
// XOR-swizzled global source; ds_read applies the same XOR (rule 21 / G4).
__global__ __launch_bounds__(256, 2) void conv_gemm_kernel(
    const __hip_bfloat16* __restrict__ wB,    // [512][4608]
    const __hip_bfloat16* __restrict__ xpad,  // [16][34][34][512]
    const float* __restrict__ rsig,           // [16][512]
    float* __restrict__ out) {                // [16][512][32][32]
  __shared__ __attribute__((aligned(16))) __hip_bfloat16 ldsW[128 * 64];
  __shared__ __attribute__((aligned(16))) __hip_bfloat16 ldsX[128 * 64];

  const int tid = threadIdx.x;
  const int wv = tid >> 6, lane = tid & 63;
  const int bo0 = blockIdx.y << 7;   // cout block
  const int bp0 = blockIdx.x << 7;   // pixel block (never crosses an image)
  const int wr = wv >> 1, wc = wv & 1;

  // staging precompute: 4 chunks of 16B per thread per tile.
  // chunk c = j*256+tid; LDS byte = c*16 (linear); row = c>>3; source chunk
  // within row is XOR-swizzled: sc = (c&7) ^ (row&7).
  int wsoff[4], xpixb[4], xsc8[4];
#pragma unroll
  for (int j = 0; j < 4; ++j) {
    const int c = j * 256 + tid;
    const int row = c >> 3;
    const int sc = (c & 7) ^ (row & 7);
    wsoff[j] = (bo0 + row) * KTOT + sc * 8;
    const int p = bp0 + row;
    const int b = p >> 10, rem = p & 1023, y = rem >> 5, xx = rem & 31;
    xpixb[j] = (b * 34 + y) * 34 + xx;  // padded top-left; tap adds (ty*34+tx)
    xsc8[j] = sc * 8;
  }

  f32x4 acc[4][4];
#pragma unroll
  for (int mi = 0; mi < 4; ++mi)
#pragma unroll
    for (int ni = 0; ni < 4; ++ni) acc[mi][ni] = f32x4{0.f, 0.f, 0.f, 0.f};

  for (int kt = 0; kt < KTOT / 64; ++kt) {   // 72 iters
    const int K0 = kt << 6;
    const int tap = K0 >> 9;                 // 512 % 64 == 0: one tap per K-step
    const int ci0 = K0 & 511;
    const int tapoff = (tap / 3) * 34 + (tap % 3);
#pragma unroll
    for (int j = 0; j < 4; ++j) {
      gload_lds16(wB + (size_t)(wsoff[j] + K0),
                  ldsW + (size_t)(j * 256 + (wv << 6)) * 8);
      gload_lds16(xpad + (size_t)(xpixb[j] + tapoff) * 512 + ci0 + xsc8[j],
                  ldsX + (size_t)(j * 256 + (wv << 6)) * 8);
    }
    __syncthreads();   // drains vmcnt -> staged data visible

#pragma unroll
    for (int kk = 0; kk < 2; ++kk) {
      bf16x8 af[4], bfr[4];
      const int kb = (kk << 6) + ((lane >> 4) << 4);
#pragma unroll
      for (int mi = 0; mi < 4; ++mi) {
        const int row = (wr << 6) + (mi << 4) + (lane & 15);
        af[mi] = *(const bf16x8*)((const char*)ldsW + row * 128 +
                                  (kb ^ ((row & 7) << 4)));
      }
#pragma unroll
      for (int ni = 0; ni < 4; ++ni) {
        const int row = (wc << 6) + (ni << 4) + (lane & 15);
        bfr[ni] = *(const bf16x8*)((const char*)ldsX + row * 128 +
                                   (kb ^ ((row & 7) << 4)));
      }
#pragma unroll
      for (int mi = 0; mi < 4; ++mi)
#pragma unroll
        for (int ni = 0; ni < 4; ++ni)
          acc[mi][ni] = __builtin_amdgcn_mfma_f32_16x16x32_bf16(
              af[mi], bfr[ni], acc[mi][ni], 0, 0, 0);
    }
    __syncthreads();   // all reads done before next stage overwrites
  }

  // epilogue: D[o][p] * rsig[b][o].  C/D: col(=p)=lane&15, row(=o)=(lane>>4)*4+r
  const int bimg = bp0 >> 10;  // pixel block never crosses an image (128 | 1024)
#pragma unroll
  for (int mi = 0; mi < 4; ++mi) {
    const int o = bo0 + (wr << 6) + (mi << 4) + ((lane >> 4) << 2);
    const f32x4 rs = *(const f32x4*)(rsig + (bimg << 9) + o);
#pragma unroll
    for (int ni = 0; ni < 4; ++ni) {
      const int p = bp0 + (wc << 6) + (ni << 4) + (lane & 15);
      const int prem = p & 1023;
#pragma unroll
      for (int r = 0; r < 4; ++r)
        out[((size_t)(bimg << 9) + o + r) * 1024 + prem] =
            acc[mi][ni][r] * rs[r];
    }
  }
}

extern "C" void kernel_launch(void* const* d_in, const int* in_sizes, int n_in,
                              void* d_out, int out_size, void* d_ws,
                              size_t ws_size, hipStream_t stream) {
  const float* x = (const float*)d_in[0];   // [16,512,32,32]
  const float* s = (const float*)d_in[1];   // [16,512]
  const float* w = (const float*)d_in[2];   // [512,512,3,3]
  float* out = (float*)d_out;               // [16,512,32,32] f32

  char* ws = (char*)d_ws;
  const size_t xpad_bytes = (size_t)NB * 34 * 34 * 512 * 2;  // 18,939,904
  const size_t wB_bytes = (size_t)COUT * KTOT * 2;           //  4,718,592
  const size_t wsq_bytes = (size_t)COUT * CIN * 4;           //  1,048,576
  __hip_bfloat16* xpad = (__hip_bfloat16*)ws;
  __hip_bfloat16* wB = (__hip_bfloat16*)(ws + xpad_bytes);
  float* wsq = (float*)(ws + xpad_bytes + wB_bytes);
  float* rsig = (float*)(ws + xpad_bytes + wB_bytes + wsq_bytes);

  hipMemsetAsync(xpad, 0, xpad_bytes, stream);  // zero halo (capturable)
  pack_w_kernel<<<(COUT * CIN) / 256, 256, 0, stream>>>(w, wB, wsq);
  modulate_kernel<<<NB * 32, 256, 0, stream>>>(x, s, xpad);
  calc_rsig_kernel<<<(NB * COUT) / 4, 256, 0, stream>>>(s, wsq, rsig);
  conv_gemm_kernel<<<dim3(NPIX / 128, COUT / 128), 256, 0, stream>>>(
      wB, xpad, rsig, out);
}